// Round 14
// baseline (14567.853 us; speedup 1.0000x reference)
//
#include <hip/hip_runtime.h>

#define BATCH   16
#define NPTS    32768
#define NPOINT  2048
#define C_FEAT  128
#define NTH     1024
#define NW      16

// ===========================================================================
// Round 14: r7's PROVEN dense skeleton (register dmin, fully-unrolled FMA
// loop, coalesced loads) + Morton sort + per-lane register bboxes for
// wave-granular exact skipping + register-memoized argmax packs.
// r11-r13 lesson: phase-decomposed lazy structures all cost ~7us/step
// regardless of barrier count -- sparse ballot-driven loops serialize
// latency. r7's dense unrolled loop pipelines it.
// Layout trick: wave-local transpose (sorted p=w*2048+l*32+k stored at
// addr=w*2048+k*64+l) -> iteration k loads 64 consecutive float4 (coalesced)
// AND lane l's 32 regs hold 32 CONSECUTIVE sorted points (tight bbox).
// Exactness: skip wave only if ALL lanes' r2*0.999 > lmax (strict: skipped
// d > dmin elementwise, 0.999 >> ulp); update = r7-VERIFIED
// fmaf(dz,dz,fmaf(dy,dy,dx*dx)); argmax via monotone u64 packs with
// key=(origidx<<15|addr), complement => min origidx on ties == np.argmax
// first-occurrence; exact & scatter-order-independent.
// ws: [fps_idx 128KB @0][pos0 @128KB][pts 8MB @1MB]
// ===========================================================================

__device__ __forceinline__ unsigned part4(unsigned v) {
  return (v & 1u) | ((v & 2u) << 2) | ((v & 4u) << 4) | ((v & 8u) << 6);
}
__device__ __forceinline__ int morton(float x, float y, float z) {
  const unsigned qx = (unsigned)min(15, max(0, (int)((x + 4.0f) * 2.0f)));
  const unsigned qy = (unsigned)min(15, max(0, (int)((y + 4.0f) * 2.0f)));
  const unsigned qz = (unsigned)min(15, max(0, (int)((z + 4.0f) * 2.0f)));
  return (int)(part4(qx) | (part4(qy) << 1) | (part4(qz) << 2));
}

// ---------------------------------------------------------------------------
// Morton counting sort; scatter into wave-local transposed layout:
// sorted pos p -> addr = (p & ~2047) | ((p&31)<<6) | ((p>>5)&63).
// pts[addr] = (x,y,z,bitcast(origidx)); pos0[b] = addr of original point 0.
// ---------------------------------------------------------------------------
__global__ __launch_bounds__(NTH) void sort_kernel(
    const float* __restrict__ xyz, float4* __restrict__ pts,
    int* __restrict__ pos0) {
  const int b = blockIdx.x, t = threadIdx.x, lane = t & 63;
  const float* __restrict__ base = xyz + (size_t)b * NPTS * 3;
  __shared__ unsigned bins[4096];
  __shared__ unsigned wsum[NW];

  for (int i = t; i < 4096; i += NTH) bins[i] = 0u;
  __syncthreads();
  for (int k = 0; k < 32; ++k) {
    const int p = k * NTH + t;
    atomicAdd(&bins[morton(base[p*3], base[p*3+1], base[p*3+2])], 1u);
  }
  __syncthreads();

  unsigned c0 = bins[4*t], c1 = bins[4*t+1], c2 = bins[4*t+2], c3 = bins[4*t+3];
  const unsigned mysum = c0 + c1 + c2 + c3;
  unsigned acc = mysum;
#pragma unroll
  for (int d = 1; d < 64; d <<= 1) {
    unsigned n = __shfl_up(acc, d);
    if (lane >= d) acc += n;
  }
  if (lane == 63) wsum[t >> 6] = acc;
  __syncthreads();
  unsigned woff = 0;
  for (int w = 0; w < (t >> 6); ++w) woff += wsum[w];
  unsigned run = woff + acc - mysum;
  bins[4*t]   = run; run += c0;
  bins[4*t+1] = run; run += c1;
  bins[4*t+2] = run; run += c2;
  bins[4*t+3] = run;
  __syncthreads();

  float4* __restrict__ pb = pts + (size_t)b * NPTS;
  for (int k = 0; k < 32; ++k) {
    const int p = k * NTH + t;
    const float x = base[p*3], y = base[p*3+1], z = base[p*3+2];
    const unsigned pos = atomicAdd(&bins[morton(x, y, z)], 1u);
    const unsigned addr = (pos & ~2047u) | ((pos & 31u) << 6) | ((pos >> 5) & 63u);
    pb[addr] = make_float4(x, y, z, __int_as_float(p));
    if (p == 0) pos0[b] = (int)addr;
  }
}

// ---------------------------------------------------------------------------
// FPS: dense r7-style loop, wave-granular exact skip, memoized argmax,
// ONE barrier per step. One block per batch.
// ---------------------------------------------------------------------------
__global__ __launch_bounds__(NTH, 4) void fps_kernel(
    const float4* __restrict__ pts_g, const int* __restrict__ pos0,
    int* __restrict__ fps_idx) {
  const int b = blockIdx.x, t = threadIdx.x, lane = t & 63, w = t >> 6;
  const float4* __restrict__ P  = pts_g + (size_t)b * NPTS;
  const float4* __restrict__ PW = P + (w << 11);        // wave's 2048 points

  __shared__ unsigned long long pack_lds[2][NW];

  // ---- init: dmin, per-lane bbox, per-lane (lmax,lkey) ----
  float dmin[32];
  float bxl = 1e30f, bxh = -1e30f, byl = 1e30f, byh = -1e30f,
        bzl = 1e30f, bzh = -1e30f;
  unsigned lkey = 0xFFFFFFFFu;
#pragma unroll
  for (int k = 0; k < 32; ++k) {
    const int a = (k << 6) + lane;
    const float4 q = PW[a];
    bxl = fminf(bxl, q.x); bxh = fmaxf(bxh, q.x);
    byl = fminf(byl, q.y); byh = fmaxf(byh, q.y);
    bzl = fminf(bzl, q.z); bzh = fmaxf(bzh, q.z);
    dmin[k] = 1e10f;
    const unsigned key =
        ((unsigned)__float_as_int(q.w) << 15) | (unsigned)((w << 11) + a);
    lkey = min(lkey, key);
  }
  float lmax = 1e10f;

  // wave memo (vm, bk): all dmin equal -> min key
  float vm = lmax; unsigned bk = lkey;
#pragma unroll
  for (int off = 32; off > 0; off >>= 1) {
    const float    ov  = __shfl_xor(vm, off);
    const unsigned obk = (unsigned)__shfl_xor((int)bk, off);
    if (ov > vm || (ov == vm && obk < bk)) { vm = ov; bk = obk; }
  }

  // start: original index 0
  int far = 0;
  const int a0 = pos0[b];
  const float4 q0 = P[a0];
  float cx = q0.x, cy = q0.y, cz = q0.z;

  for (int s = 0; s < NPOINT; ++s) {
    if (t == 0) fps_idx[b * NPOINT + s] = far;

    // ---- per-lane exact prune test (registers only) ----
    const float ddx = fmaxf(fmaxf(bxl - cx, cx - bxh), 0.0f);
    const float ddy = fmaxf(fmaxf(byl - cy, cy - byh), 0.0f);
    const float ddz = fmaxf(fmaxf(bzl - cz, cz - bzh), 0.0f);
    const float r2 = ddx * ddx + ddy * ddy + ddz * ddz;
    const bool need = !(r2 * 0.999f > lmax);

    if (__ballot(need)) {           // wave-uniform
      // ---- dense r7-style update, fully unrolled, coalesced ----
      lmax = -1.0f; lkey = 0xFFFFFFFFu;
#pragma unroll
      for (int k = 0; k < 32; ++k) {
        const int a = (k << 6) + lane;
        const float4 q = PW[a];
        const float dx = q.x - cx, dy = q.y - cy, dz = q.z - cz;
        // EXACT reference pipeline (verified round 7):
        const float d = __builtin_fmaf(dz, dz, __builtin_fmaf(dy, dy, dx * dx));
        const float nd = fminf(dmin[k], d);
        dmin[k] = nd;
        const unsigned key =
            ((unsigned)__float_as_int(q.w) << 15) | (unsigned)((w << 11) + a);
        if (nd > lmax)       { lmax = nd; lkey = key; }
        else if (nd == lmax) { lkey = min(lkey, key); }
      }
      // wave (val,key) argmax reduce, tie -> min key (min origidx)
      vm = lmax; bk = lkey;
#pragma unroll
      for (int off = 32; off > 0; off >>= 1) {
        const float    ov  = __shfl_xor(vm, off);
        const unsigned obk = (unsigned)__shfl_xor((int)bk, off);
        if (ov > vm || (ov == vm && obk < bk)) { vm = ov; bk = obk; }
      }
    }
    // memoized pack (valid whether updated or skipped)
    if (lane == 0)
      pack_lds[s & 1][w] =
          ((unsigned long long)__float_as_uint(vm) << 32) |
          (unsigned long long)(0x3FFFFFFFu - bk);
    __syncthreads();                                   // the ONE barrier

    // ---- global argmax: 16 packs, 4-shfl u64 max ----
    unsigned long long p = pack_lds[s & 1][lane & 15];
#pragma unroll
    for (int off = 8; off > 0; off >>= 1) {
      const unsigned lo = (unsigned)p, hi = (unsigned)(p >> 32);
      const unsigned olo = (unsigned)__shfl_xor((int)lo, off);
      const unsigned ohi = (unsigned)__shfl_xor((int)hi, off);
      const unsigned long long op = ((unsigned long long)ohi << 32) | olo;
      if (op > p) p = op;
    }
    const unsigned kwin = 0x3FFFFFFFu - (unsigned)(p & 0x3FFFFFFFu);
    far = (int)(kwin >> 15);
    const int aw = (int)(kwin & 0x7FFFu);
    const float4 qn = P[aw];        // broadcast L2/L1 load
    cx = qn.x; cy = qn.y; cz = qn.z;
  }
}

// ---------------------------------------------------------------------------
// Gather: [B][NPOINT][3] then [B][NPOINT][128], concatenated flat.
// ---------------------------------------------------------------------------
__global__ __launch_bounds__(256) void gather_kernel(
    const float* __restrict__ xyz, const float* __restrict__ feat,
    const int* __restrict__ fps_idx, float* __restrict__ out) {
  const int lane = threadIdx.x & 31;
  const int sub  = threadIdx.x >> 5;
  const int row  = blockIdx.x * 8 + sub;
  const int b    = row >> 11;
  const int src  = fps_idx[row];

  const float4* __restrict__ f =
      reinterpret_cast<const float4*>(feat + ((size_t)b * NPTS + src) * C_FEAT);
  float4* __restrict__ o =
      reinterpret_cast<float4*>(out + (size_t)BATCH * NPOINT * 3 +
                                (size_t)row * C_FEAT);
  o[lane] = f[lane];
  if (lane < 3) {
    out[(size_t)row * 3 + lane] = xyz[((size_t)b * NPTS + src) * 3 + lane];
  }
}

extern "C" void kernel_launch(void* const* d_in, const int* in_sizes, int n_in,
                              void* d_out, int out_size, void* d_ws, size_t ws_size,
                              hipStream_t stream) {
  (void)in_sizes; (void)n_in; (void)out_size; (void)ws_size;
  const float* xyz  = (const float*)d_in[0];
  const float* feat = (const float*)d_in[1];
  float* out = (float*)d_out;

  char* ws = (char*)d_ws;
  int*    fps_idx = (int*)ws;                     // 128 KB @ 0
  int*    pos0    = (int*)(ws + (1u << 17));      // 64 B  @ 128KB
  float4* pts     = (float4*)(ws + (1u << 20));   // 8 MB  @ 1MB

  sort_kernel<<<BATCH, NTH, 0, stream>>>(xyz, pts, pos0);
  fps_kernel<<<BATCH, NTH, 0, stream>>>(pts, pos0, fps_idx);
  gather_kernel<<<(BATCH * NPOINT) / 8, 256, 0, stream>>>(xyz, feat, fps_idx, out);
}

// Round 16
// 4761.408 us; speedup vs baseline: 3.0596x; 3.0596x over previous
//
#include <hip/hip_runtime.h>

#define BATCH   16
#define NPTS    32768
#define NPOINT  2048
#define C_FEAT  128
#define NSEG    512           // 64 Morton-consecutive points per segment
#define NTH     1024
#define NW      16

// ===========================================================================
// Round 16 = round 15 + ONE fix: phase-0 compaction executed by ALL lanes
// (ballot + shfl hoisted out of the divergent branch). r15's
// `__shfl(wb,0)` inside `if(need)` read an INACTIVE lane 0 when lane 0
// wasn't needy -> undefined worklist base -> dropped/corrupted seg updates
// (absmax 9.375). Everything else is byte-identical to r15.
// Design recap: work-shared lazy FPS -- needy segs compacted to a worklist
// scanned by ALL 16 waves (dense 1-load body) so L2 latency is hidden by
// TLP (r8-r14 lesson); dmin in LDS; memoized per-seg (cmax,argkey) u64
// packs; 3 barriers/step; no global atomics; no dmin==M rescan.
// Exactness: skip seg only if r2*0.999 > cmax (exact member bbox, fp error
// ~4ulp << margin); update = r7-VERIFIED fmaf(dz,dz,fmaf(dy,dy,dx*dx));
// u64-max pack = (max cmax, tie -> min ORIGINAL idx) == np.argmax
// first-occurrence; scatter-order-independent.
// ws: [fps_idx 128KB @0][pos0 @128KB][pts 8MB @1MB]
// ===========================================================================

__device__ __forceinline__ unsigned part4(unsigned v) {
  return (v & 1u) | ((v & 2u) << 2) | ((v & 4u) << 4) | ((v & 8u) << 6);
}
__device__ __forceinline__ int morton(float x, float y, float z) {
  const unsigned qx = (unsigned)min(15, max(0, (int)((x + 4.0f) * 2.0f)));
  const unsigned qy = (unsigned)min(15, max(0, (int)((y + 4.0f) * 2.0f)));
  const unsigned qz = (unsigned)min(15, max(0, (int)((z + 4.0f) * 2.0f)));
  return (int)(part4(qx) | (part4(qy) << 1) | (part4(qz) << 2));
}

__device__ __forceinline__ unsigned long long u64max(unsigned long long a,
                                                     unsigned long long b) {
  return a > b ? a : b;
}

// ---------------------------------------------------------------------------
// Morton counting sort: pts[pos] = (x,y,z,bitcast(origidx)) in sorted order;
// pos0[b] = sorted position of original point 0.
// ---------------------------------------------------------------------------
__global__ __launch_bounds__(NTH) void sort_kernel(
    const float* __restrict__ xyz, float4* __restrict__ pts,
    int* __restrict__ pos0) {
  const int b = blockIdx.x, t = threadIdx.x, lane = t & 63;
  const float* __restrict__ base = xyz + (size_t)b * NPTS * 3;
  __shared__ unsigned bins[4096];
  __shared__ unsigned wsum[NW];

  for (int i = t; i < 4096; i += NTH) bins[i] = 0u;
  __syncthreads();
  for (int k = 0; k < 32; ++k) {
    const int p = k * NTH + t;
    atomicAdd(&bins[morton(base[p*3], base[p*3+1], base[p*3+2])], 1u);
  }
  __syncthreads();

  unsigned c0 = bins[4*t], c1 = bins[4*t+1], c2 = bins[4*t+2], c3 = bins[4*t+3];
  const unsigned mysum = c0 + c1 + c2 + c3;
  unsigned acc = mysum;
#pragma unroll
  for (int d = 1; d < 64; d <<= 1) {
    unsigned n = __shfl_up(acc, d);
    if (lane >= d) acc += n;
  }
  if (lane == 63) wsum[t >> 6] = acc;
  __syncthreads();
  unsigned woff = 0;
  for (int w = 0; w < (t >> 6); ++w) woff += wsum[w];
  unsigned run = woff + acc - mysum;
  bins[4*t]   = run; run += c0;
  bins[4*t+1] = run; run += c1;
  bins[4*t+2] = run; run += c2;
  bins[4*t+3] = run;
  __syncthreads();

  float4* __restrict__ pb = pts + (size_t)b * NPTS;
  for (int k = 0; k < 32; ++k) {
    const int p = k * NTH + t;
    const float x = base[p*3], y = base[p*3+1], z = base[p*3+2];
    const unsigned pos = atomicAdd(&bins[morton(x, y, z)], 1u);
    pb[pos] = make_float4(x, y, z, __int_as_float(p));
    if (p == 0) pos0[b] = (int)pos;
  }
}

// ---------------------------------------------------------------------------
// Work-shared lazy FPS. One block per batch; 3 barriers/step.
// ---------------------------------------------------------------------------
__global__ __launch_bounds__(NTH) void fps_kernel(
    const float4* __restrict__ pts_g, const int* __restrict__ pos0,
    int* __restrict__ fps_idx) {
  const int b = blockIdx.x, t = threadIdx.x, lane = t & 63, w = t >> 6;
  const float4* __restrict__ P = pts_g + (size_t)b * NPTS;

  __shared__ float              dmin[NPTS];      // 128 KB
  __shared__ float              sb[6][NSEG];     // 12 KB: xl,xh,yl,yh,zl,zh
  __shared__ unsigned long long pack[NSEG];      // 4 KB
  __shared__ unsigned long long s_red[2][8];     // 128 B
  __shared__ unsigned short     wl[NSEG];        // 1 KB
  __shared__ int                s_cnt[2];

  // ---- init: dmin, per-seg exact bbox + initial pack (all dmin equal) ----
  for (int r = 0; r < 32; ++r) {
    const int seg = w * 32 + r;
    const int i = seg * 64 + lane;
    const float4 q = P[i];
    dmin[i] = 1e10f;
    float xl = q.x, xh = q.x, yl = q.y, yh = q.y, zl = q.z, zh = q.z;
    unsigned k = ((unsigned)__float_as_int(q.w) << 15) | (unsigned)i;
#pragma unroll
    for (int off = 32; off > 0; off >>= 1) {
      xl = fminf(xl, __shfl_xor(xl, off)); xh = fmaxf(xh, __shfl_xor(xh, off));
      yl = fminf(yl, __shfl_xor(yl, off)); yh = fmaxf(yh, __shfl_xor(yh, off));
      zl = fminf(zl, __shfl_xor(zl, off)); zh = fmaxf(zh, __shfl_xor(zh, off));
      k  = min(k, (unsigned)__shfl_xor((int)k, off));
    }
    if (lane == 0) {
      sb[0][seg] = xl; sb[1][seg] = xh;
      sb[2][seg] = yl; sb[3][seg] = yh;
      sb[4][seg] = zl; sb[5][seg] = zh;
      pack[seg] = ((unsigned long long)__float_as_uint(1e10f) << 32) |
                  (unsigned long long)(0x3FFFFFFFu - k);
    }
  }
  if (t == 0) { s_cnt[0] = 0; s_cnt[1] = 0; }
  __syncthreads();

  int far = 0;
  const float4 q0 = P[pos0[b]];
  float cx = q0.x, cy = q0.y, cz = q0.z;

  for (int s = 0; s < NPOINT; ++s) {
    if (t == 0) fps_idx[b * NPOINT + s] = far;
    if (t == NTH - 1) s_cnt[(s + 1) & 1] = 0;   // reset other-parity slot

    // ---- phase 0: predicate + compact (ALL lanes active for ballot/shfl) --
    if (t < NSEG) {
      const unsigned long long pk = pack[t];
      const float cm = __uint_as_float((unsigned)(pk >> 32));
      const float ddx = fmaxf(fmaxf(sb[0][t] - cx, cx - sb[1][t]), 0.0f);
      const float ddy = fmaxf(fmaxf(sb[2][t] - cy, cy - sb[3][t]), 0.0f);
      const float ddz = fmaxf(fmaxf(sb[4][t] - cz, cz - sb[5][t]), 0.0f);
      const float r2 = ddx * ddx + ddy * ddy + ddz * ddz;
      const bool need = !(r2 * 0.999f > cm);
      const unsigned long long bal = __ballot(need);        // all lanes
      int wb = 0;
      if (lane == 0 && bal != 0ull)
        wb = atomicAdd(&s_cnt[s & 1], (int)__popcll(bal));
      wb = __shfl(wb, 0);                                   // all lanes active
      if (need) {
        const unsigned long long ltm = (1ull << lane) - 1ull;
        wl[wb + (int)__popcll(bal & ltm)] = (unsigned short)t;
      }
    }
    __syncthreads();                                          // B1

    // ---- phase 1: ALL 16 waves co-scan the needy segs (dense body) ----
    const int C = s_cnt[s & 1];
    for (int e = w; e < C; e += NW) {
      const int seg = (int)wl[e];
      const int i = seg * 64 + lane;
      const float4 q = P[i];                    // coalesced 1KB/wave
      const float dx = q.x - cx, dy = q.y - cy, dz = q.z - cz;
      // EXACT reference pipeline (verified round 7):
      const float d = __builtin_fmaf(dz, dz, __builtin_fmaf(dy, dy, dx * dx));
      const float nd = fminf(dmin[i], d);
      dmin[i] = nd;                             // 2 lanes/bank: conflict-free
      float vm = nd;
      unsigned bk = ((unsigned)__float_as_int(q.w) << 15) | (unsigned)i;
#pragma unroll
      for (int off = 32; off > 0; off >>= 1) {
        const float    ov  = __shfl_xor(vm, off);
        const unsigned obk = (unsigned)__shfl_xor((int)bk, off);
        if (ov > vm || (ov == vm && obk < bk)) { vm = ov; bk = obk; }
      }
      if (lane == 0)
        pack[seg] = ((unsigned long long)__float_as_uint(vm) << 32) |
                    (unsigned long long)(0x3FFFFFFFu - bk);
    }
    __syncthreads();                                          // B2

    // ---- phase 2: u64-max over 512 packs ----
    if (t < NSEG) {
      unsigned long long p = pack[t];
#pragma unroll
      for (int off = 32; off > 0; off >>= 1) {
        const unsigned lo = (unsigned)p, hi = (unsigned)(p >> 32);
        const unsigned olo = (unsigned)__shfl_xor((int)lo, off);
        const unsigned ohi = (unsigned)__shfl_xor((int)hi, off);
        p = u64max(p, ((unsigned long long)ohi << 32) | olo);
      }
      if (lane == 0) s_red[s & 1][w] = p;
    }
    __syncthreads();                                          // B3

    unsigned long long p = s_red[s & 1][0];
#pragma unroll
    for (int j = 1; j < 8; ++j) p = u64max(p, s_red[s & 1][j]);
    const unsigned kwin = 0x3FFFFFFFu - (unsigned)(p & 0x3FFFFFFFu);
    far = (int)(kwin >> 15);
    const float4 qn = P[(int)(kwin & 0x7FFFu)];   // broadcast L2 load
    cx = qn.x; cy = qn.y; cz = qn.z;
  }
}

// ---------------------------------------------------------------------------
// Gather: [B][NPOINT][3] then [B][NPOINT][128], concatenated flat.
// ---------------------------------------------------------------------------
__global__ __launch_bounds__(256) void gather_kernel(
    const float* __restrict__ xyz, const float* __restrict__ feat,
    const int* __restrict__ fps_idx, float* __restrict__ out) {
  const int lane = threadIdx.x & 31;
  const int sub  = threadIdx.x >> 5;
  const int row  = blockIdx.x * 8 + sub;
  const int b    = row >> 11;
  const int src  = fps_idx[row];

  const float4* __restrict__ f =
      reinterpret_cast<const float4*>(feat + ((size_t)b * NPTS + src) * C_FEAT);
  float4* __restrict__ o =
      reinterpret_cast<float4*>(out + (size_t)BATCH * NPOINT * 3 +
                                (size_t)row * C_FEAT);
  o[lane] = f[lane];
  if (lane < 3) {
    out[(size_t)row * 3 + lane] = xyz[((size_t)b * NPTS + src) * 3 + lane];
  }
}

extern "C" void kernel_launch(void* const* d_in, const int* in_sizes, int n_in,
                              void* d_out, int out_size, void* d_ws, size_t ws_size,
                              hipStream_t stream) {
  (void)in_sizes; (void)n_in; (void)out_size; (void)ws_size;
  const float* xyz  = (const float*)d_in[0];
  const float* feat = (const float*)d_in[1];
  float* out = (float*)d_out;

  char* ws = (char*)d_ws;
  int*    fps_idx = (int*)ws;                     // 128 KB @ 0
  int*    pos0    = (int*)(ws + (1u << 17));      // 64 B  @ 128KB
  float4* pts     = (float4*)(ws + (1u << 20));   // 8 MB  @ 1MB

  sort_kernel<<<BATCH, NTH, 0, stream>>>(xyz, pts, pos0);
  fps_kernel<<<BATCH, NTH, 0, stream>>>(pts, pos0, fps_idx);
  gather_kernel<<<(BATCH * NPOINT) / 8, 256, 0, stream>>>(xyz, feat, fps_idx, out);
}